// Round 1
// baseline (8902.022 us; speedup 1.0000x reference)
//
#include <hip/hip_runtime.h>
#include <math.h>

#define BB 4096
#define TT 256
#define NIN 8
#define H1 100
#define H2 50
#define G1 400  // 4*H1
#define G2 200  // 4*H2
#define ROWS 16
#define NT 256

__device__ __forceinline__ float sigf(float x) {
    return __builtin_amdgcn_rcpf(1.0f + __expf(-x));
}
__device__ __forceinline__ float tanhfast(float x) {
    // tanh(x) = 1 - 2/(exp(2x)+1); saturates correctly at +/-inf
    return 1.0f - 2.0f * __builtin_amdgcn_rcpf(1.0f + __expf(2.0f * x));
}

__global__ __launch_bounds__(NT) void lstm_fused(
    const float* __restrict__ x,
    const float* __restrict__ W_ih1, const float* __restrict__ W_hh1,
    const float* __restrict__ b_ih1, const float* __restrict__ b_hh1,
    const float* __restrict__ W_ih2, const float* __restrict__ W_hh2,
    const float* __restrict__ b_ih2, const float* __restrict__ b_hh2,
    const float* __restrict__ Wd, const float* __restrict__ bd,
    float* __restrict__ out)
{
    __shared__ float h1[ROWS][H1];
    __shared__ float h2[ROWS][H2];
    __shared__ float g1s[ROWS][G1];
    __shared__ float g2s[ROWS][G2];
    __shared__ float xc[ROWS][NIN];
    __shared__ float bs1[G1];
    __shared__ float bs2[G2];

    const int tid = threadIdx.x;
    const int row0 = blockIdx.x * ROWS;

    // one-time init
    for (int i = tid; i < G1; i += NT) bs1[i] = b_ih1[i] + b_hh1[i];
    for (int i = tid; i < G2; i += NT) bs2[i] = b_ih2[i] + b_hh2[i];
    for (int i = tid; i < ROWS * H1; i += NT) (&h1[0][0])[i] = 0.f;
    for (int i = tid; i < ROWS * H2; i += NT) (&h2[0][0])[i] = 0.f;

    // fixed task->(row,unit) maps so cell state can live in registers
    int r1t[7], u1t[7];
    float c1r[7];
#pragma unroll
    for (int it = 0; it < 7; ++it) {
        int task = tid + it * NT;
        r1t[it] = task / H1;
        u1t[it] = task % H1;
        c1r[it] = 0.f;
    }
    int r2t[4], u2t[4];
    float c2r[4];
#pragma unroll
    for (int it = 0; it < 4; ++it) {
        int task = tid + it * NT;
        r2t[it] = task / H2;
        u2t[it] = task % H2;
        c2r[it] = 0.f;
    }

    __syncthreads();

    for (int t = 0; t < TT; ++t) {
        // stage x[:, t, :] for this block's rows
        if (tid < ROWS * NIN) {
            int r = tid >> 3, k = tid & 7;
            xc[r][k] = x[(size_t)(row0 + r) * (TT * NIN) + t * NIN + k];
        }
        __syncthreads();

        // ---- phase 1a: layer-1 gate pre-activations ----
        for (int j = tid; j < G1; j += NT) {
            float acc[ROWS];
            float b = bs1[j];
#pragma unroll
            for (int r = 0; r < ROWS; ++r) acc[r] = b;
            const float* wi = W_ih1 + j * NIN;
#pragma unroll
            for (int k = 0; k < NIN; ++k) {
                float w = wi[k];
#pragma unroll
                for (int r = 0; r < ROWS; ++r) acc[r] = fmaf(w, xc[r][k], acc[r]);
            }
            const float* wh = W_hh1 + j * H1;
#pragma unroll 4
            for (int k = 0; k < H1; ++k) {
                float w = wh[k];
#pragma unroll
                for (int r = 0; r < ROWS; ++r) acc[r] = fmaf(w, h1[r][k], acc[r]);
            }
#pragma unroll
            for (int r = 0; r < ROWS; ++r) g1s[r][j] = acc[r];
        }
        __syncthreads();

        // ---- phase 1b: layer-1 nonlinearity + state update ----
#pragma unroll
        for (int it = 0; it < 7; ++it) {
            int task = tid + it * NT;
            if (task < ROWS * H1) {
                int r = r1t[it], u = u1t[it];
                float gi = g1s[r][u];
                float gf = g1s[r][u + H1];
                float gg = g1s[r][u + 2 * H1];
                float go = g1s[r][u + 3 * H1];
                float c = sigf(gf) * c1r[it] + sigf(gi) * tanhfast(gg);
                c1r[it] = c;
                h1[r][u] = sigf(go) * tanhfast(c);
            }
        }
        __syncthreads();

        // ---- phase 2a: layer-2 gate pre-activations ----
        if (tid < G2) {
            int j = tid;
            float acc[ROWS];
            float b = bs2[j];
#pragma unroll
            for (int r = 0; r < ROWS; ++r) acc[r] = b;
            const float* wi = W_ih2 + j * H1;
#pragma unroll 4
            for (int k = 0; k < H1; ++k) {
                float w = wi[k];
#pragma unroll
                for (int r = 0; r < ROWS; ++r) acc[r] = fmaf(w, h1[r][k], acc[r]);
            }
            const float* wh = W_hh2 + j * H2;
#pragma unroll 2
            for (int k = 0; k < H2; ++k) {
                float w = wh[k];
#pragma unroll
                for (int r = 0; r < ROWS; ++r) acc[r] = fmaf(w, h2[r][k], acc[r]);
            }
#pragma unroll
            for (int r = 0; r < ROWS; ++r) g2s[r][j] = acc[r];
        }
        __syncthreads();

        // ---- phase 2b: layer-2 nonlinearity + state update ----
#pragma unroll
        for (int it = 0; it < 4; ++it) {
            int task = tid + it * NT;
            if (task < ROWS * H2) {
                int r = r2t[it], u = u2t[it];
                float gi = g2s[r][u];
                float gf = g2s[r][u + H2];
                float gg = g2s[r][u + 2 * H2];
                float go = g2s[r][u + 3 * H2];
                float c = sigf(gf) * c2r[it] + sigf(gi) * tanhfast(gg);
                c2r[it] = c;
                h2[r][u] = sigf(go) * tanhfast(c);
            }
        }
        __syncthreads();
    }

    // ---- final dense: out = h2 @ Wd^T + bd ----
    if (tid < ROWS) {
        float acc = bd[0];
#pragma unroll 2
        for (int u = 0; u < H2; ++u) acc = fmaf(h2[tid][u], Wd[u], acc);
        out[row0 + tid] = acc;
    }
}

extern "C" void kernel_launch(void* const* d_in, const int* in_sizes, int n_in,
                              void* d_out, int out_size, void* d_ws, size_t ws_size,
                              hipStream_t stream) {
    const float* x     = (const float*)d_in[0];
    const float* W_ih1 = (const float*)d_in[1];
    const float* W_hh1 = (const float*)d_in[2];
    const float* b_ih1 = (const float*)d_in[3];
    const float* b_hh1 = (const float*)d_in[4];
    const float* W_ih2 = (const float*)d_in[5];
    const float* W_hh2 = (const float*)d_in[6];
    const float* b_ih2 = (const float*)d_in[7];
    const float* b_hh2 = (const float*)d_in[8];
    const float* Wd    = (const float*)d_in[9];
    const float* bd    = (const float*)d_in[10];
    float* out = (float*)d_out;

    hipLaunchKernelGGL(lstm_fused, dim3(BB / ROWS), dim3(NT), 0, stream,
                       x, W_ih1, W_hh1, b_ih1, b_hh1,
                       W_ih2, W_hh2, b_ih2, b_hh2, Wd, bd, out);
}

// Round 2
// 4588.416 us; speedup vs baseline: 1.9401x; 1.9401x over previous
//
#include <hip/hip_runtime.h>
#include <math.h>

#define BB 4096
#define TT 256
#define NIN 8
#define H1 100
#define H2 50
#define G1 400  // 4*H1
#define G2 200  // 4*H2
#define ROWS 8
#define NT 256
#define NBLK (BB / ROWS)  // 512 blocks -> 2 blocks/CU

__device__ __forceinline__ float sigf(float x) {
    return __builtin_amdgcn_rcpf(1.0f + __expf(-x));
}
__device__ __forceinline__ float tanhfast(float x) {
    // tanh(x) = 1 - 2/(exp(2x)+1); saturates correctly
    return 1.0f - 2.0f * __builtin_amdgcn_rcpf(1.0f + __expf(2.0f * x));
}

__device__ __forceinline__ void fma8(float wv, const float4& ha, const float4& hb,
                                     float acc[ROWS]) {
    acc[0] = fmaf(wv, ha.x, acc[0]);
    acc[1] = fmaf(wv, ha.y, acc[1]);
    acc[2] = fmaf(wv, ha.z, acc[2]);
    acc[3] = fmaf(wv, ha.w, acc[3]);
    acc[4] = fmaf(wv, hb.x, acc[4]);
    acc[5] = fmaf(wv, hb.y, acc[5]);
    acc[6] = fmaf(wv, hb.z, acc[6]);
    acc[7] = fmaf(wv, hb.w, acc[7]);
}

__global__ __launch_bounds__(NT, 2) void lstm_fused(
    const float* __restrict__ x,
    const float* __restrict__ W_ih1, const float* __restrict__ W_hh1,
    const float* __restrict__ b_ih1, const float* __restrict__ b_hh1,
    const float* __restrict__ W_ih2, const float* __restrict__ W_hh2,
    const float* __restrict__ b_ih2, const float* __restrict__ b_hh2,
    const float* __restrict__ Wd, const float* __restrict__ bd,
    float* __restrict__ out)
{
    // transposed state: [unit][row], rows contiguous -> b128 broadcast reads
    __shared__ __align__(16) float h1T[H1][ROWS];   // 3.2 KB
    __shared__ __align__(16) float h2T[H2][ROWS];   // 1.6 KB
    __shared__ __align__(16) float xcT[NIN][ROWS];  // 256 B
    __shared__ __align__(16) float g1s[ROWS][G1 + 1];  // 12.8 KB
    __shared__ __align__(16) float g2s[ROWS][G2 + 1];  // 6.4 KB
    __shared__ float bs1[G1];
    __shared__ float bs2[G2];

    const int tid = threadIdx.x;
    const int row0 = blockIdx.x * ROWS;

    // one-time init
    for (int i = tid; i < G1; i += NT) bs1[i] = b_ih1[i] + b_hh1[i];
    for (int i = tid; i < G2; i += NT) bs2[i] = b_ih2[i] + b_hh2[i];
    for (int i = tid; i < H1 * ROWS; i += NT) (&h1T[0][0])[i] = 0.f;
    for (int i = tid; i < H2 * ROWS; i += NT) (&h2T[0][0])[i] = 0.f;

    float c1r[4];
#pragma unroll
    for (int it = 0; it < 4; ++it) c1r[it] = 0.f;
    float c2r[2];
#pragma unroll
    for (int it = 0; it < 2; ++it) c2r[it] = 0.f;

    // x prefetch: one element per thread for tid < 64
    const int xr = tid >> 3, xk = tid & 7;
    float xreg = 0.f;
    if (tid < ROWS * NIN)
        xreg = x[(size_t)(row0 + xr) * (TT * NIN) + 0 * NIN + xk];

    __syncthreads();

    for (int t = 0; t < TT; ++t) {
        if (tid < ROWS * NIN) {
            xcT[xk][xr] = xreg;  // write perm of 0..63 -> 2-way max, free
            if (t + 1 < TT)
                xreg = x[(size_t)(row0 + xr) * (TT * NIN) + (t + 1) * NIN + xk];
        }
        __syncthreads();

        // ---- phase 1a: layer-1 gate pre-activations ----
        for (int j = tid; j < G1; j += NT) {
            float acc[ROWS];
            const float b = bs1[j];
#pragma unroll
            for (int r = 0; r < ROWS; ++r) acc[r] = b;

            const float4* wi4 = reinterpret_cast<const float4*>(W_ih1 + j * NIN);
#pragma unroll
            for (int kk = 0; kk < NIN / 4; ++kk) {
                float4 w = wi4[kk];
                const float* wp = reinterpret_cast<const float*>(&w);
#pragma unroll
                for (int c = 0; c < 4; ++c) {
                    const int k = kk * 4 + c;
                    float4 ha = *reinterpret_cast<const float4*>(&xcT[k][0]);
                    float4 hb = *reinterpret_cast<const float4*>(&xcT[k][4]);
                    fma8(wp[c], ha, hb, acc);
                }
            }
            const float4* wh4 = reinterpret_cast<const float4*>(W_hh1 + j * H1);
#pragma unroll 5
            for (int kk = 0; kk < H1 / 4; ++kk) {
                float4 w = wh4[kk];
                const float* wp = reinterpret_cast<const float*>(&w);
#pragma unroll
                for (int c = 0; c < 4; ++c) {
                    const int k = kk * 4 + c;
                    float4 ha = *reinterpret_cast<const float4*>(&h1T[k][0]);
                    float4 hb = *reinterpret_cast<const float4*>(&h1T[k][4]);
                    fma8(wp[c], ha, hb, acc);
                }
            }
#pragma unroll
            for (int r = 0; r < ROWS; ++r) g1s[r][j] = acc[r];
        }
        __syncthreads();

        // ---- phase 1b: layer-1 nonlinearity + state update ----
#pragma unroll
        for (int it = 0; it < 4; ++it) {
            const int task = tid + it * NT;
            if (task < ROWS * H1) {
                const int r = task & (ROWS - 1), u = task >> 3;
                const float gi = g1s[r][u];
                const float gf = g1s[r][u + H1];
                const float gg = g1s[r][u + 2 * H1];
                const float go = g1s[r][u + 3 * H1];
                const float cc = sigf(gf) * c1r[it] + sigf(gi) * tanhfast(gg);
                c1r[it] = cc;
                h1T[u][r] = sigf(go) * tanhfast(cc);  // lane-consecutive write
            }
        }
        __syncthreads();

        // ---- phase 2a: layer-2 gate pre-activations ----
        if (tid < G2) {
            const int j = tid;
            float acc[ROWS];
            const float b = bs2[j];
#pragma unroll
            for (int r = 0; r < ROWS; ++r) acc[r] = b;

            const float4* wi4 = reinterpret_cast<const float4*>(W_ih2 + j * H1);
#pragma unroll 5
            for (int kk = 0; kk < H1 / 4; ++kk) {
                float4 w = wi4[kk];
                const float* wp = reinterpret_cast<const float*>(&w);
#pragma unroll
                for (int c = 0; c < 4; ++c) {
                    const int k = kk * 4 + c;
                    float4 ha = *reinterpret_cast<const float4*>(&h1T[k][0]);
                    float4 hb = *reinterpret_cast<const float4*>(&h1T[k][4]);
                    fma8(wp[c], ha, hb, acc);
                }
            }
            const float2* wh2 = reinterpret_cast<const float2*>(W_hh2 + j * H2);
#pragma unroll 5
            for (int kk = 0; kk < H2 / 2; ++kk) {
                float2 w = wh2[kk];
                const float* wp = reinterpret_cast<const float*>(&w);
#pragma unroll
                for (int c = 0; c < 2; ++c) {
                    const int k = kk * 2 + c;
                    float4 ha = *reinterpret_cast<const float4*>(&h2T[k][0]);
                    float4 hb = *reinterpret_cast<const float4*>(&h2T[k][4]);
                    fma8(wp[c], ha, hb, acc);
                }
            }
#pragma unroll
            for (int r = 0; r < ROWS; ++r) g2s[r][j] = acc[r];
        }
        __syncthreads();

        // ---- phase 2b: layer-2 nonlinearity + state update ----
#pragma unroll
        for (int it = 0; it < 2; ++it) {
            const int task = tid + it * NT;
            if (task < ROWS * H2) {
                const int r = task & (ROWS - 1), u = task >> 3;
                const float gi = g2s[r][u];
                const float gf = g2s[r][u + H2];
                const float gg = g2s[r][u + 2 * H2];
                const float go = g2s[r][u + 3 * H2];
                const float cc = sigf(gf) * c2r[it] + sigf(gi) * tanhfast(gg);
                c2r[it] = cc;
                h2T[u][r] = sigf(go) * tanhfast(cc);
            }
        }
        __syncthreads();
    }

    // ---- final dense: out = h2 @ Wd^T + bd ----
    if (tid < ROWS) {
        float acc = bd[0];
#pragma unroll 2
        for (int u = 0; u < H2; ++u) acc = fmaf(h2T[u][tid], Wd[u], acc);
        out[row0 + tid] = acc;
    }
}

extern "C" void kernel_launch(void* const* d_in, const int* in_sizes, int n_in,
                              void* d_out, int out_size, void* d_ws, size_t ws_size,
                              hipStream_t stream) {
    const float* x     = (const float*)d_in[0];
    const float* W_ih1 = (const float*)d_in[1];
    const float* W_hh1 = (const float*)d_in[2];
    const float* b_ih1 = (const float*)d_in[3];
    const float* b_hh1 = (const float*)d_in[4];
    const float* W_ih2 = (const float*)d_in[5];
    const float* W_hh2 = (const float*)d_in[6];
    const float* b_ih2 = (const float*)d_in[7];
    const float* b_hh2 = (const float*)d_in[8];
    const float* Wd    = (const float*)d_in[9];
    const float* bd    = (const float*)d_in[10];
    float* out = (float*)d_out;

    hipLaunchKernelGGL(lstm_fused, dim3(NBLK), dim3(NT), 0, stream,
                       x, W_ih1, W_hh1, b_ih1, b_hh1,
                       W_ih2, W_hh2, b_ih2, b_hh2, Wd, bd, out);
}

// Round 3
// 469.213 us; speedup vs baseline: 18.9723x; 9.7790x over previous
//
#include <hip/hip_runtime.h>
#include <math.h>

#define TT 256
#define NIN 8
#define H1 100
#define H2 50
#define NT 512
#define NBLK 256   // 4096 rows / 16 per block; 1 block per CU

typedef __attribute__((ext_vector_type(8))) short bf16x8;
typedef __attribute__((ext_vector_type(4))) float f32x4;

__device__ __forceinline__ float sigf(float x) {
    return __builtin_amdgcn_rcpf(1.0f + __expf(-x));
}
__device__ __forceinline__ float tanhfast(float x) {
    // tanh(x) = 1 - 2/(exp(2x)+1); saturates correctly at +/-inf
    return 1.0f - 2.0f * __builtin_amdgcn_rcpf(1.0f + __expf(2.0f * x));
}
__device__ __forceinline__ short f2bf(float f) {
    union { float f; unsigned u; } v; v.f = f;
    unsigned r = v.u + 0x7FFFu + ((v.u >> 16) & 1u);  // RNE
    return (short)(r >> 16);
}

// D = A*B: A = W' tile [16 j' x 32 k] (VGPR-resident), B = h^T [32 k x 16 r]
// read from row-major h[r][k] LDS as 8 contiguous bf16 per lane.
// C/D: col(lane&15) = r, row((lane>>4)*4+reg) = j' = 4u+gate -> per-lane i,f,g,o.

__global__ __launch_bounds__(NT, 2) void lstm_mfma(
    const float* __restrict__ x,
    const float* __restrict__ W_ih1, const float* __restrict__ W_hh1,
    const float* __restrict__ b_ih1, const float* __restrict__ b_hh1,
    const float* __restrict__ W_ih2, const float* __restrict__ W_hh2,
    const float* __restrict__ b_ih2, const float* __restrict__ b_hh2,
    const float* __restrict__ Wd, const float* __restrict__ bd,
    float* __restrict__ out)
{
    // h-state buffers (B^T layout, XOR-swizzled). Row strides are 256B/512B
    // (powers of 2) so byte^((r&7)<<4) stays inside the row.
    __shared__ short A1h[16 * 128];  // k: 0..99 h1 | 100..107 x | 108..127 zeros
    __shared__ short A2h[16 * 256];  // k: 0..99 h1 | 100..149 h2 | 150..255 zeros

    const int tid = threadIdx.x;
    const int lane = tid & 63;
    const int wv = tid >> 6;        // 8 waves
    const int r = lane & 15;        // batch row (D col / B col / A1h row)
    const int q = lane >> 4;        // k-subblock for frags; u-offset for acc
    const int row0 = blockIdx.x * 16;
    const int swz = (r & 7) << 4;

    char* a1c = (char*)A1h;
    char* a2c = (char*)A2h;

    // ---- zero LDS state ----
    for (int i = tid; i < 16 * 128; i += NT) A1h[i] = 0;
    for (int i = tid; i < 16 * 256; i += NT) A2h[i] = 0;

    // ---- tile assignment (wave-uniform) ----
    int gt1[4]; int nt1 = (wv == 0) ? 4 : 3;
    gt1[0] = wv; gt1[1] = wv + 8; gt1[2] = wv + 16; gt1[3] = 24;
    int gt2[2]; int nt2 = (wv >= 1 && wv <= 5) ? 2 : 1;
    gt2[0] = wv; gt2[1] = wv + 7;   // waves 1..5 own tiles 8..12

    // ---- persistent weight fragments in VGPRs (loaded once) ----
    bf16x8 w1f[4][4];
#pragma unroll
    for (int tt = 0; tt < 4; ++tt) {
        const int jp = gt1[tt] * 16 + r;          // A-frag row = j'
        const int g = jp & 3, uu = jp >> 2;       // j' = 4u + gate
        const int srow = g * H1 + uu;
#pragma unroll
        for (int c = 0; c < 4; ++c) {
#pragma unroll
            for (int i = 0; i < 8; ++i) {
                const int k = c * 32 + q * 8 + i;
                float f = 0.f;
                if (k < H1) f = W_hh1[srow * H1 + k];
                else if (k < H1 + NIN) f = W_ih1[srow * NIN + (k - H1)];
                w1f[tt][c][i] = f2bf(f);
            }
        }
    }
    bf16x8 w2f[2][5];
#pragma unroll
    for (int tt = 0; tt < 2; ++tt) {
        const int jp = gt2[tt] * 16 + r;
        const int g = jp & 3, uu = jp >> 2;
#pragma unroll
        for (int c = 0; c < 5; ++c) {
#pragma unroll
            for (int i = 0; i < 8; ++i) {
                const int k = c * 32 + q * 8 + i;
                float f = 0.f;
                if (uu < H2) {
                    const int srow = g * H2 + uu;
                    if (k < 100) f = W_ih2[srow * 100 + k];
                    else if (k < 150) f = W_hh2[srow * 50 + (k - 100)];
                }
                w2f[tt][c][i] = f2bf(f);
            }
        }
    }

    // ---- biases (f32, VGPR-resident) ----
    f32x4 bias1v[4];
#pragma unroll
    for (int tt = 0; tt < 4; ++tt) {
        const int u = gt1[tt] * 4 + q;            // acc's unit
#pragma unroll
        for (int g = 0; g < 4; ++g)
            bias1v[tt][g] = b_ih1[g * H1 + u] + b_hh1[g * H1 + u];
    }
    f32x4 bias2v[2];
#pragma unroll
    for (int tt = 0; tt < 2; ++tt) {
        const int u2 = gt2[tt] * 4 + q;
#pragma unroll
        for (int g = 0; g < 4; ++g)
            bias2v[tt][g] = (u2 < H2) ? (b_ih2[g * H2 + u2] + b_hh2[g * H2 + u2]) : 0.f;
    }

    // ---- precomputed swizzled LDS addresses ----
    int b1addr[4], b2addr[5];
#pragma unroll
    for (int c = 0; c < 4; ++c) b1addr[c] = r * 256 + (((c * 32 + q * 8) * 2) ^ swz);
#pragma unroll
    for (int c = 0; c < 5; ++c) b2addr[c] = r * 512 + (((c * 32 + q * 8) * 2) ^ swz);
    int h1wa[4], h2wa[4], h2wb[2];
#pragma unroll
    for (int tt = 0; tt < 4; ++tt) {
        const int u = gt1[tt] * 4 + q;
        h1wa[tt] = r * 256 + ((u * 2) ^ swz);
        h2wa[tt] = r * 512 + ((u * 2) ^ swz);
    }
#pragma unroll
    for (int tt = 0; tt < 2; ++tt) {
        const int u2 = gt2[tt] * 4 + q;
        h2wb[tt] = r * 512 + (((100 + u2) * 2) ^ swz);
    }

    // ---- cell states ----
    float c1s[4] = {0.f, 0.f, 0.f, 0.f};
    float c2s[2] = {0.f, 0.f};

    // ---- x staging: tid<128 owns (row xr, feature xk) ----
    const int xr = tid >> 3, xk = tid & 7;
    const int xwaddr = xr * 256 + (((H1 + xk) * 2) ^ ((xr & 7) << 4));

    __syncthreads();
    if (tid < 128) {  // write x(0)
        float x0 = x[((size_t)(row0 + xr) * TT + 0) * NIN + xk];
        *(short*)(a1c + xwaddr) = f2bf(x0);
    }
    __syncthreads();

    for (int t = 0; t < TT; ++t) {
        // prefetch x(t+1) (consumed in P2; latency hidden under P1)
        float xnext = 0.f;
        if (tid < 128 && t + 1 < TT)
            xnext = x[((size_t)(row0 + xr) * TT + (t + 1)) * NIN + xk];

        // ---- P1: layer-1 MFMAs (read A1h) ----
        f32x4 acc1[4];
#pragma unroll
        for (int tt = 0; tt < 4; ++tt) acc1[tt] = bias1v[tt];
#pragma unroll
        for (int c = 0; c < 4; ++c) {
            bf16x8 b = *(const bf16x8*)(a1c + b1addr[c]);
#pragma unroll
            for (int tt = 0; tt < 4; ++tt)
                if (tt < nt1)
                    acc1[tt] = __builtin_amdgcn_mfma_f32_16x16x32_bf16(
                        w1f[tt][c], b, acc1[tt], 0, 0, 0);
        }
        __syncthreads();  // all A1h reads done

        // ---- P2: layer-1 nonlinearity, write h1 + x(t+1) ----
#pragma unroll
        for (int tt = 0; tt < 4; ++tt) {
            if (tt < nt1) {
                const float gi = acc1[tt][0], gf = acc1[tt][1];
                const float gg = acc1[tt][2], go = acc1[tt][3];
                const float cc = sigf(gf) * c1s[tt] + sigf(gi) * tanhfast(gg);
                c1s[tt] = cc;
                const float h = sigf(go) * tanhfast(cc);
                const short hb = f2bf(h);
                *(short*)(a1c + h1wa[tt]) = hb;
                *(short*)(a2c + h2wa[tt]) = hb;
            }
        }
        if (tid < 128) *(short*)(a1c + xwaddr) = f2bf(xnext);
        __syncthreads();  // h1/x visible

        // ---- P3: layer-2 MFMAs (read A2h) ----
        f32x4 acc2[2];
#pragma unroll
        for (int tt = 0; tt < 2; ++tt) acc2[tt] = bias2v[tt];
#pragma unroll
        for (int c = 0; c < 5; ++c) {
            bf16x8 b = *(const bf16x8*)(a2c + b2addr[c]);
#pragma unroll
            for (int tt = 0; tt < 2; ++tt)
                if (tt < nt2)
                    acc2[tt] = __builtin_amdgcn_mfma_f32_16x16x32_bf16(
                        w2f[tt][c], b, acc2[tt], 0, 0, 0);
        }
        __syncthreads();  // all A2h reads done

        // ---- P4: layer-2 nonlinearity, write h2 ----
#pragma unroll
        for (int tt = 0; tt < 2; ++tt) {
            const int u2 = gt2[tt] * 4 + q;
            if (tt < nt2 && u2 < H2) {
                const float gi = acc2[tt][0], gf = acc2[tt][1];
                const float gg = acc2[tt][2], go = acc2[tt][3];
                const float cc = sigf(gf) * c2s[tt] + sigf(gi) * tanhfast(gg);
                c2s[tt] = cc;
                const float h = sigf(go) * tanhfast(cc);
                *(short*)(a2c + h2wb[tt]) = f2bf(h);
                if (t == TT - 1) {
                    // final h2 in fp32 for the dense head (reuse A1h as scratch)
                    ((float*)A1h)[r * H2 + u2] = h;
                }
            }
        }
        // no barrier needed: P4 writes A2h k100..149 / A1h-scratch; next
        // readers are P3' (two barriers away) and the post-loop dense.
    }

    __syncthreads();
    // ---- dense head: out = h2 @ Wd^T + bd ----
    if (tid < 16) {
        const float* scr = (const float*)A1h;
        float acc = bd[0];
#pragma unroll 2
        for (int u = 0; u < H2; ++u) acc = fmaf(scr[tid * H2 + u], Wd[u], acc);
        out[row0 + tid] = acc;
    }
}

extern "C" void kernel_launch(void* const* d_in, const int* in_sizes, int n_in,
                              void* d_out, int out_size, void* d_ws, size_t ws_size,
                              hipStream_t stream) {
    const float* x     = (const float*)d_in[0];
    const float* W_ih1 = (const float*)d_in[1];
    const float* W_hh1 = (const float*)d_in[2];
    const float* b_ih1 = (const float*)d_in[3];
    const float* b_hh1 = (const float*)d_in[4];
    const float* W_ih2 = (const float*)d_in[5];
    const float* W_hh2 = (const float*)d_in[6];
    const float* b_ih2 = (const float*)d_in[7];
    const float* b_hh2 = (const float*)d_in[8];
    const float* Wd    = (const float*)d_in[9];
    const float* bd    = (const float*)d_in[10];
    float* out = (float*)d_out;

    hipLaunchKernelGGL(lstm_mfma, dim3(NBLK), dim3(NT), 0, stream,
                       x, W_ih1, W_hh1, b_ih1, b_hh1,
                       W_ih2, W_hh2, b_ih2, b_hh2, Wd, bd, out);
}

// Round 4
// 402.806 us; speedup vs baseline: 22.1000x; 1.1649x over previous
//
#include <hip/hip_runtime.h>
#include <math.h>

#define TT 256
#define H1 100
#define H2 50
#define NT 512
#define NBLK 256   // 4096 rows / 16 per block; 1 block per CU
#define ROWS 16

typedef __attribute__((ext_vector_type(8))) short bf16x8;
typedef __attribute__((ext_vector_type(4))) float f32x4;

__device__ __forceinline__ float sigf(float x) {
    return __builtin_amdgcn_rcpf(1.0f + __expf(-x));
}
__device__ __forceinline__ float tanhfast(float x) {
    return 1.0f - 2.0f * __builtin_amdgcn_rcpf(1.0f + __expf(2.0f * x));
}
__device__ __forceinline__ short f2bf(float f) {
    union { float f; unsigned u; } v; v.f = f;
    unsigned r = v.u + 0x7FFFu + ((v.u >> 16) & 1u);  // RNE
    return (short)(r >> 16);
}

// fragment-linear byte offset inside one [4|2 chunks][64 lanes][8 bf16] buffer
// for element (K, R): lane = ((K&31)>>3)*16 + R, elem i = K&7, chunk = K>>5.
__device__ __forceinline__ int off_frag(int K, int R) {
    return (K >> 5) * 1024 + ((K >> 3) & 3) * 256 + R * 16 + (K & 7) * 2;
}

#define MFMA16(acc, w, b) \
    acc = __builtin_amdgcn_mfma_f32_16x16x32_bf16(w, b, acc, 0, 0, 0)

__device__ __forceinline__ float cellup(const f32x4& a, float& cst) {
    const float is = sigf(a[0]), fs = sigf(a[1]);
    const float gt = tanhfast(a[2]), os = sigf(a[3]);
    const float c = fs * cst + is * gt;
    cst = c;
    return os * tanhfast(c);
}

// ---- weight fragment loaders (run once; scalar loads OK) ----
// A-frag row = lane&15 -> j' = T*16 + r; gate g = j'&3, unit u = j'>>2.
__device__ __forceinline__ void load_w1(bf16x8* dst, int T, int r, int q,
                                        const float* W_hh1, const float* W_ih1) {
    const int jp = T * 16 + r, g = jp & 3, uu = jp >> 2;  // uu < 100
#pragma unroll
    for (int c = 0; c < 4; ++c) {
        bf16x8 w;
#pragma unroll
        for (int i = 0; i < 8; ++i) {
            const int k = c * 32 + q * 8 + i;
            float f = 0.f;
            if (k < H1) f = W_hh1[(g * H1 + uu) * H1 + k];          // h1(t-1) part
            else if (k < H1 + 8) f = W_ih1[(g * H1 + uu) * 8 + (k - H1)];  // x(t)
            w[i] = f2bf(f);
        }
        dst[c] = w;
    }
}
__device__ __forceinline__ void load_w2(bf16x8* dst, int t2, int r, int q,
                                        const float* W_ih2, const float* W_hh2) {
    const int jp = t2 * 16 + r, g = jp & 3, uu = jp >> 2;
    const bool ok = uu < H2;
#pragma unroll
    for (int c = 0; c < 6; ++c) {
        bf16x8 w;
#pragma unroll
        for (int i = 0; i < 8; ++i) {
            float f = 0.f;
            if (ok) {
                if (c < 4) {
                    const int k = c * 32 + q * 8 + i;               // h1(t) part
                    if (k < H1) f = W_ih2[(g * H2 + uu) * H1 + k];  // x cols -> 0
                } else {
                    const int k2 = (c - 4) * 32 + q * 8 + i;        // h2(t-1) part
                    if (k2 < H2) f = W_hh2[(g * H2 + uu) * H2 + k2];
                }
            }
            w[i] = f2bf(f);
        }
        dst[c] = w;
    }
}

__global__ __launch_bounds__(NT, 2) void lstm_ws(
    const float* __restrict__ x,
    const float* __restrict__ W_ih1, const float* __restrict__ W_hh1,
    const float* __restrict__ b_ih1, const float* __restrict__ b_hh1,
    const float* __restrict__ W_ih2, const float* __restrict__ W_hh2,
    const float* __restrict__ b_ih2, const float* __restrict__ b_hh2,
    const float* __restrict__ Wd, const float* __restrict__ bd,
    float* __restrict__ out)
{
    __shared__ __align__(16) short xb[TT * ROWS * 8];   // 64 KB: [t][r][k] bf16
    __shared__ __align__(16) short A1h[2 * 4 * 64 * 8]; // 8 KB: [buf][chunk][lane][8]
    __shared__ __align__(16) short h2b[2 * 2 * 64 * 8]; // 4 KB
    __shared__ float hscr[ROWS * 52];                   // 3.3 KB final h2 f32

    const int tid = threadIdx.x;
    const int lane = tid & 63;
    const int wv = tid >> 6;       // 8 waves
    const int r = lane & 15;       // batch row
    const int q = lane >> 4;       // k-subblock
    const int row0 = blockIdx.x * ROWS;

    // ---- fill xb (x -> bf16, [t][r][k] fragment-friendly layout) ----
    {
        const float* xg = x + (size_t)row0 * (TT * 8);
        for (int it = 0; it < 16; ++it) {
            const int f4 = it * NT + tid;          // 0..8191
            const int f = f4 * 4;
            const float4 v = *(const float4*)(xg + f);
            const int rr = f >> 11, rem = f & 2047, t = rem >> 3, k = rem & 7;
            uint2 pk;
            pk.x = (unsigned short)f2bf(v.x) | ((unsigned)(unsigned short)f2bf(v.y) << 16);
            pk.y = (unsigned short)f2bf(v.z) | ((unsigned)(unsigned short)f2bf(v.w) << 16);
            *(uint2*)((char*)xb + t * 256 + rr * 16 + k * 2) = pk;
        }
    }
    // ---- zero state buffers (pads must stay zero forever) ----
    for (int i = tid; i < 2 * 4 * 64 * 8; i += NT) A1h[i] = 0;
    for (int i = tid; i < 2 * 2 * 64 * 8; i += NT) h2b[i] = 0;

    // ---- slot composition ----
    // slots 0..2: L1 tile T = wv + sl*8 (0..23)
    // slot 3: wv==0 -> L1 tile 24; wv 1..5 -> L2 tile wv+7; wv 6,7 -> none
    // slot 4: L2 tile wv (0..7)
    bf16x8 wfA[3][4];
    bf16x8 wfB[6];
    bf16x8 wfC[6];
    f32x4 bv[5];
    float cst[5] = {0.f, 0.f, 0.f, 0.f, 0.f};
    int wofs[5] = {0, 0, 0, 0, 0};
    int hso3 = 0, hso4 = 0;
    bool ok3 = false;

#pragma unroll
    for (int sl = 0; sl < 3; ++sl) {
        const int T = wv + sl * 8;
        load_w1(wfA[sl], T, r, q, W_hh1, W_ih1);
        const int u = T * 4 + q;
#pragma unroll
        for (int g = 0; g < 4; ++g) bv[sl][g] = b_ih1[g * H1 + u] + b_hh1[g * H1 + u];
        wofs[sl] = off_frag(u, r);
    }
    if (wv == 0) {
        load_w1(wfB, 24, r, q, W_hh1, W_ih1);
        const int u = 96 + q;
#pragma unroll
        for (int g = 0; g < 4; ++g) bv[3][g] = b_ih1[g * H1 + u] + b_hh1[g * H1 + u];
        wofs[3] = off_frag(u, r);
    } else if (wv <= 5) {
        load_w2(wfB, wv + 7, r, q, W_ih2, W_hh2);
        const int u2 = (wv + 7) * 4 + q;
        ok3 = (u2 < H2);
#pragma unroll
        for (int g = 0; g < 4; ++g)
            bv[3][g] = ok3 ? (b_ih2[g * H2 + u2] + b_hh2[g * H2 + u2]) : 0.f;
        wofs[3] = off_frag(u2 & 63, r);
        hso3 = r * 52 + u2;
    }
    {
        load_w2(wfC, wv, r, q, W_ih2, W_hh2);
        const int u2 = wv * 4 + q;   // <= 31, always valid
#pragma unroll
        for (int g = 0; g < 4; ++g) bv[4][g] = b_ih2[g * H2 + u2] + b_hh2[g * H2 + u2];
        wofs[4] = off_frag(u2, r);
        hso4 = r * 52 + u2;
    }

    __syncthreads();

    // ---- stage x(0) into A1h buf0 (k = 100..107) ----
    if (tid < ROWS) {
        bf16x8 v = *(const bf16x8*)((const char*)xb + 0 * 256 + tid * 16);
        uint2 lo = ((const uint2*)&v)[0], hi = ((const uint2*)&v)[1];
        char* dst = (char*)A1h + 3 * 1024 + tid * 16;
        *(uint2*)(dst + 8) = lo;          // k 100..103 -> q'0, i 4..7
        *(uint2*)(dst + 256) = hi;        // k 104..107 -> q'1, i 0..3
    }
    __syncthreads();

    // ==== main loop: superstep s; L1 computes h1(s), L2 computes h2(s-1) ====
    for (int s = 0; s <= TT; ++s) {
        const int cur = s & 1;
        char* a1r = (char*)A1h + cur * 4096;
        char* h2r = (char*)h2b + cur * 2048;
        char* a1w = (char*)A1h + (cur ^ 1) * 4096;
        char* h2w = (char*)h2b + (cur ^ 1) * 2048;

        // B-fragments: pure stride-1 (base + lane*16) -> conflict-free
        const bf16x8 bA0 = *(const bf16x8*)(a1r + 0 * 1024 + lane * 16);
        const bf16x8 bA1 = *(const bf16x8*)(a1r + 1 * 1024 + lane * 16);
        const bf16x8 bA2 = *(const bf16x8*)(a1r + 2 * 1024 + lane * 16);
        const bf16x8 bA3 = *(const bf16x8*)(a1r + 3 * 1024 + lane * 16);
        const bf16x8 bH0 = *(const bf16x8*)(h2r + 0 * 1024 + lane * 16);
        const bf16x8 bH1 = *(const bf16x8*)(h2r + 1 * 1024 + lane * 16);

        // stage x(s+1) into write buffer (LDS->LDS, wave 7 lanes 0..15)
        if ((tid >> 4) == 28 && s + 1 < TT) {
            const int st = tid & 15;
            bf16x8 v = *(const bf16x8*)((const char*)xb + (s + 1) * 256 + st * 16);
            uint2 lo = ((const uint2*)&v)[0], hi = ((const uint2*)&v)[1];
            char* dst = a1w + 3 * 1024 + st * 16;
            *(uint2*)(dst + 8) = lo;
            *(uint2*)(dst + 256) = hi;
        }

        // ---- L1 tiles (valid for s < TT) ----
        if (s < TT) {
#pragma unroll
            for (int sl = 0; sl < 3; ++sl) {
                f32x4 a = bv[sl];
                MFMA16(a, wfA[sl][0], bA0);
                MFMA16(a, wfA[sl][1], bA1);
                MFMA16(a, wfA[sl][2], bA2);
                MFMA16(a, wfA[sl][3], bA3);
                const float h = cellup(a, cst[sl]);
                *(short*)(a1w + wofs[sl]) = f2bf(h);
            }
            if (wv == 0) {  // slot 3 as L1 tile 24
                f32x4 a = bv[3];
                MFMA16(a, wfB[0], bA0);
                MFMA16(a, wfB[1], bA1);
                MFMA16(a, wfB[2], bA2);
                MFMA16(a, wfB[3], bA3);
                const float h = cellup(a, cst[3]);
                *(short*)(a1w + wofs[3]) = f2bf(h);
            }
        }
        // ---- L2 tiles (valid for s > 0; compute h2(s-1)) ----
        if (s > 0) {
            if (wv >= 1 && wv <= 5) {  // slot 3 as L2 tile
                f32x4 a = bv[3];
                MFMA16(a, wfB[0], bA0);
                MFMA16(a, wfB[1], bA1);
                MFMA16(a, wfB[2], bA2);
                MFMA16(a, wfB[3], bA3);
                MFMA16(a, wfB[4], bH0);
                MFMA16(a, wfB[5], bH1);
                const float h = cellup(a, cst[3]);
                if (ok3) {
                    if (s < TT) *(short*)(h2w + wofs[3]) = f2bf(h);
                    else        hscr[hso3] = h;      // final h2(255) in f32
                }
            }
            {  // slot 4 (all waves)
                f32x4 a = bv[4];
                MFMA16(a, wfC[0], bA0);
                MFMA16(a, wfC[1], bA1);
                MFMA16(a, wfC[2], bA2);
                MFMA16(a, wfC[3], bA3);
                MFMA16(a, wfC[4], bH0);
                MFMA16(a, wfC[5], bH1);
                const float h = cellup(a, cst[4]);
                if (s < TT) *(short*)(h2w + wofs[4]) = f2bf(h);
                else        hscr[hso4] = h;
            }
        }
        __syncthreads();
    }

    // ---- dense head: out = h2 @ Wd^T + bd ----
    if (tid < ROWS) {
        float acc = bd[0];
#pragma unroll 2
        for (int u = 0; u < H2; ++u) acc = fmaf(hscr[tid * 52 + u], Wd[u], acc);
        out[row0 + tid] = acc;
    }
}

extern "C" void kernel_launch(void* const* d_in, const int* in_sizes, int n_in,
                              void* d_out, int out_size, void* d_ws, size_t ws_size,
                              hipStream_t stream) {
    const float* x     = (const float*)d_in[0];
    const float* W_ih1 = (const float*)d_in[1];
    const float* W_hh1 = (const float*)d_in[2];
    const float* b_ih1 = (const float*)d_in[3];
    const float* b_hh1 = (const float*)d_in[4];
    const float* W_ih2 = (const float*)d_in[5];
    const float* W_hh2 = (const float*)d_in[6];
    const float* b_ih2 = (const float*)d_in[7];
    const float* b_hh2 = (const float*)d_in[8];
    const float* Wd    = (const float*)d_in[9];
    const float* bd    = (const float*)d_in[10];
    float* out = (float*)d_out;

    hipLaunchKernelGGL(lstm_ws, dim3(NBLK), dim3(NT), 0, stream,
                       x, W_ih1, W_hh1, b_ih1, b_hh1,
                       W_ih2, W_hh2, b_ih2, b_hh2, Wd, bd, out);
}

// Round 7
// 379.957 us; speedup vs baseline: 23.4290x; 1.0601x over previous
//
#include <hip/hip_runtime.h>
#include <math.h>

#define TT 256
#define H1 100
#define H2 50
#define NT 512
#define NBLK 256   // 4096 rows / 16 per block; 1 block per CU
#define ROWS 16

typedef __attribute__((ext_vector_type(8))) short bf16x8;
typedef __attribute__((ext_vector_type(4))) float f32x4;

__device__ __forceinline__ float sigf(float x) {
    return __builtin_amdgcn_rcpf(1.0f + __expf(-x));
}
__device__ __forceinline__ float tanhfast(float x) {
    return 1.0f - 2.0f * __builtin_amdgcn_rcpf(1.0f + __expf(2.0f * x));
}
__device__ __forceinline__ short f2bf(float f) {
    union { float f; unsigned u; } v; v.f = f;
    unsigned r = v.u + 0x7FFFu + ((v.u >> 16) & 1u);  // RNE
    return (short)(r >> 16);
}

// fragment-linear byte offset: element (K,R) of a [chunk][64 lane][8 bf16] buf
__device__ __forceinline__ int off_frag(int K, int R) {
    return (K >> 5) * 1024 + ((K >> 3) & 3) * 256 + R * 16 + (K & 7) * 2;
}

#define MFMA(w, b, c) __builtin_amdgcn_mfma_f32_16x16x32_bf16(w, b, c, 0, 0, 0)

__device__ __forceinline__ float cellup(const f32x4& a, float& cst) {
    const float is = sigf(a[0]), fs = sigf(a[1]);
    const float gt = tanhfast(a[2]), os = sigf(a[3]);
    const float c = fs * cst + is * gt;
    cst = c;
    return os * tanhfast(c);
}

// ---- weight fragment loaders (round-4 proven; run once) ----
__device__ __forceinline__ void load_w1(bf16x8* dst, int T, int r, int q,
                                        const float* W_hh1, const float* W_ih1) {
    const int jp = T * 16 + r, g = jp & 3, uu = jp >> 2;   // uu < 100
#pragma unroll
    for (int c = 0; c < 4; ++c) {
        bf16x8 w;
#pragma unroll
        for (int i = 0; i < 8; ++i) {
            const int k = c * 32 + q * 8 + i;
            float f = 0.f;
            if (k < H1) f = W_hh1[(g * H1 + uu) * H1 + k];
            else if (k < H1 + 8) f = W_ih1[(g * H1 + uu) * 8 + (k - H1)];
            w[i] = f2bf(f);
        }
        dst[c] = w;
    }
}
__device__ __forceinline__ void load_w2(bf16x8* dst, int t2, int r, int q,
                                        const float* W_ih2, const float* W_hh2) {
    const int jp = t2 * 16 + r, g = jp & 3, uu = jp >> 2;
    const bool ok = uu < H2;
#pragma unroll
    for (int c = 0; c < 6; ++c) {
        bf16x8 w;
#pragma unroll
        for (int i = 0; i < 8; ++i) {
            float f = 0.f;
            if (ok) {
                if (c < 4) {
                    const int k = c * 32 + q * 8 + i;
                    if (k < H1) f = W_ih2[(g * H2 + uu) * H1 + k];
                } else {
                    const int k2 = (c - 4) * 32 + q * 8 + i;
                    if (k2 < H2) f = W_hh2[(g * H2 + uu) * H2 + k2];
                }
            }
            w[i] = f2bf(f);
        }
        dst[c] = w;
    }
}

__global__ __launch_bounds__(NT, 2) void lstm_ws3(
    const float* __restrict__ x,
    const float* __restrict__ W_ih1, const float* __restrict__ W_hh1,
    const float* __restrict__ b_ih1, const float* __restrict__ b_hh1,
    const float* __restrict__ W_ih2, const float* __restrict__ W_hh2,
    const float* __restrict__ b_ih2, const float* __restrict__ b_hh2,
    const float* __restrict__ Wd, const float* __restrict__ bd,
    float* __restrict__ out)
{
    __shared__ __align__(16) short xb[TT * ROWS * 8];   // 64 KB bf16 x
    __shared__ __align__(16) short A1h[2 * 4 * 64 * 8]; // 8 KB
    __shared__ __align__(16) short h2b[2 * 2 * 64 * 8]; // 4 KB
    __shared__ float hscr[ROWS * 52];

    const int tid = threadIdx.x;
    const int lane = tid & 63;
    const int wv = tid >> 6;
    const int r = lane & 15;
    const int q = lane >> 4;
    const int row0 = blockIdx.x * ROWS;

    char* const a1b = (char*)A1h;
    char* const h2bb = (char*)h2b;

    // ---- fill xb (round-4 proven path) ----
    {
        const float* xg = x + (size_t)row0 * (TT * 8);
        for (int it = 0; it < 16; ++it) {
            const int f = (it * NT + tid) * 4;
            const float4 v = *(const float4*)(xg + f);
            const int rr = f >> 11, rem = f & 2047, t = rem >> 3, k = rem & 7;
            uint2 pk;
            pk.x = (unsigned short)f2bf(v.x) | ((unsigned)(unsigned short)f2bf(v.y) << 16);
            pk.y = (unsigned short)f2bf(v.z) | ((unsigned)(unsigned short)f2bf(v.w) << 16);
            *(uint2*)((char*)xb + t * 256 + rr * 16 + k * 2) = pk;
        }
    }
    for (int i = tid; i < 2 * 4 * 64 * 8; i += NT) A1h[i] = 0;
    for (int i = tid; i < 2 * 2 * 64 * 8; i += NT) h2b[i] = 0;

    // ---- persistent weights + biases (unscaled, round-4 numerics) ----
    bf16x8 wfA0[4], wfA1[4], wfA2[4], wfB[6], wfC[6];
    f32x4 bv0, bv1, bv2, bv3 = {0.f, 0.f, 0.f, 0.f}, bv4;
    int wof0, wof1, wof2, wof3 = 0, wof4;
    int hso3 = 0, hso4;
    bool ok3 = false;

    load_w1(wfA0, wv + 0, r, q, W_hh1, W_ih1);
    load_w1(wfA1, wv + 8, r, q, W_hh1, W_ih1);
    load_w1(wfA2, wv + 16, r, q, W_hh1, W_ih1);
    {
        const int u0 = (wv + 0) * 4 + q, u1 = (wv + 8) * 4 + q, u2_ = (wv + 16) * 4 + q;
#pragma unroll
        for (int g = 0; g < 4; ++g) {
            bv0[g] = b_ih1[g * H1 + u0] + b_hh1[g * H1 + u0];
            bv1[g] = b_ih1[g * H1 + u1] + b_hh1[g * H1 + u1];
            bv2[g] = b_ih1[g * H1 + u2_] + b_hh1[g * H1 + u2_];
        }
        wof0 = off_frag(u0, r); wof1 = off_frag(u1, r); wof2 = off_frag(u2_, r);
    }
    if (wv == 0) {            // slot3 = L1 tile 24
        load_w1(wfB, 24, r, q, W_hh1, W_ih1);
        wfB[4] = (bf16x8){0,0,0,0,0,0,0,0};
        wfB[5] = (bf16x8){0,0,0,0,0,0,0,0};
        const int u = 96 + q;
#pragma unroll
        for (int g = 0; g < 4; ++g) bv3[g] = b_ih1[g * H1 + u] + b_hh1[g * H1 + u];
        wof3 = off_frag(u, r);
        ok3 = true;
    } else if (wv <= 5) {     // slot3 = L2 tile wv+7
        load_w2(wfB, wv + 7, r, q, W_ih2, W_hh2);
        const int u2 = (wv + 7) * 4 + q;
        ok3 = (u2 < H2);
#pragma unroll
        for (int g = 0; g < 4; ++g)
            bv3[g] = ok3 ? (b_ih2[g * H2 + u2] + b_hh2[g * H2 + u2]) : 0.f;
        wof3 = off_frag(u2 & 63, r);
        hso3 = r * 52 + u2;
    } else {                  // wv 6,7: dead slot3 (uniform shape, no store)
#pragma unroll
        for (int c = 0; c < 6; ++c) wfB[c] = (bf16x8){0,0,0,0,0,0,0,0};
    }
    {                          // slot4 = L2 tile wv (u2 <= 31, always valid)
        load_w2(wfC, wv, r, q, W_ih2, W_hh2);
        const int u2 = wv * 4 + q;
#pragma unroll
        for (int g = 0; g < 4; ++g) bv4[g] = b_ih2[g * H2 + u2] + b_hh2[g * H2 + u2];
        wof4 = off_frag(u2, r);
        hso4 = r * 52 + u2;
    }

    float cst0 = 0.f, cst1 = 0.f, cst2 = 0.f, cst3 = 0.f, cst4 = 0.f;

    const bool wstage = ((tid >> 4) == 28);   // wave 7, lanes 0..15
    const int st = tid & 15;

    __syncthreads();
    // stage x(0) into buf0
    if (tid < ROWS) {
        bf16x8 v = *(const bf16x8*)((const char*)xb + tid * 16);
        uint2 lo = ((const uint2*)&v)[0], hi = ((const uint2*)&v)[1];
        char* dst = a1b + 3 * 1024 + tid * 16;
        *(uint2*)(dst + 8) = lo;
        *(uint2*)(dst + 256) = hi;
    }
    __syncthreads();

    // ==== main loop: superstep s computes h1(s) and (s>0) h2(s-1) ====
    for (int s = 0; s < TT; ++s) {
        const int cur = s & 1;
        char* a1r = a1b + (cur << 12);
        char* h2r = h2bb + (cur << 11);
        char* a1w = a1b + ((cur ^ 1) << 12);
        char* h2w = h2bb + ((cur ^ 1) << 11);

        const bf16x8 bA0 = *(const bf16x8*)(a1r + 0 * 1024 + lane * 16);
        const bf16x8 bA1 = *(const bf16x8*)(a1r + 1 * 1024 + lane * 16);
        const bf16x8 bA2 = *(const bf16x8*)(a1r + 2 * 1024 + lane * 16);
        const bf16x8 bA3 = *(const bf16x8*)(a1r + 3 * 1024 + lane * 16);
        const bf16x8 bH0 = *(const bf16x8*)(h2r + 0 * 1024 + lane * 16);
        const bf16x8 bH1 = *(const bf16x8*)(h2r + 1 * 1024 + lane * 16);

        if (wstage && s + 1 < TT) {
            bf16x8 v = *(const bf16x8*)((const char*)xb + (s + 1) * 256 + st * 16);
            uint2 lo = ((const uint2*)&v)[0], hi = ((const uint2*)&v)[1];
            char* dst = a1w + 3 * 1024 + st * 16;
            *(uint2*)(dst + 8) = lo;
            *(uint2*)(dst + 256) = hi;
        }

        // ---- 24 MFMAs, 5-way interleaved; first op consumes bias as C ----
        f32x4 a0 = MFMA(wfA0[0], bA0, bv0);
        f32x4 a1 = MFMA(wfA1[0], bA0, bv1);
        f32x4 a2 = MFMA(wfA2[0], bA0, bv2);
        f32x4 a3 = MFMA(wfB[0], bA0, bv3);
        f32x4 a4 = MFMA(wfC[0], bA0, bv4);
        a0 = MFMA(wfA0[1], bA1, a0);
        a1 = MFMA(wfA1[1], bA1, a1);
        a2 = MFMA(wfA2[1], bA1, a2);
        a3 = MFMA(wfB[1], bA1, a3);
        a4 = MFMA(wfC[1], bA1, a4);
        a0 = MFMA(wfA0[2], bA2, a0);
        a1 = MFMA(wfA1[2], bA2, a1);
        a2 = MFMA(wfA2[2], bA2, a2);
        a3 = MFMA(wfB[2], bA2, a3);
        a4 = MFMA(wfC[2], bA2, a4);
        a0 = MFMA(wfA0[3], bA3, a0);
        a1 = MFMA(wfA1[3], bA3, a1);
        a2 = MFMA(wfA2[3], bA3, a2);
        a3 = MFMA(wfB[3], bA3, a3);
        a4 = MFMA(wfC[3], bA3, a4);
        a3 = MFMA(wfB[4], bH0, a3);
        a4 = MFMA(wfC[4], bH0, a4);
        a3 = MFMA(wfB[5], bH1, a3);
        a4 = MFMA(wfC[5], bH1, a4);

        // ---- nonlinearities + state writes (round-4 numerics) ----
        const float h0 = cellup(a0, cst0);
        const float h1v = cellup(a1, cst1);
        const float h2v = cellup(a2, cst2);
        *(short*)(a1w + wof0) = f2bf(h0);
        *(short*)(a1w + wof1) = f2bf(h1v);
        *(short*)(a1w + wof2) = f2bf(h2v);

        if (s > 0) {
            const float h4v = cellup(a4, cst4);
            *(short*)(h2w + wof4) = f2bf(h4v);
        }
        if (wv == 0 || (s > 0 && wv <= 5)) {
            const float h3v = cellup(a3, cst3);
            char* d3 = (wv == 0) ? a1w : h2w;
            if (ok3) *(short*)(d3 + wof3) = f2bf(h3v);
        }
        __syncthreads();
    }

    // ==== peeled final superstep (s=256): L2 computes h2(255) -> hscr ====
    {
        char* a1r = a1b;      // s=256 even -> buf0
        char* h2r = h2bb;
        const bf16x8 bA0 = *(const bf16x8*)(a1r + 0 * 1024 + lane * 16);
        const bf16x8 bA1 = *(const bf16x8*)(a1r + 1 * 1024 + lane * 16);
        const bf16x8 bA2 = *(const bf16x8*)(a1r + 2 * 1024 + lane * 16);
        const bf16x8 bA3 = *(const bf16x8*)(a1r + 3 * 1024 + lane * 16);
        const bf16x8 bH0 = *(const bf16x8*)(h2r + 0 * 1024 + lane * 16);
        const bf16x8 bH1 = *(const bf16x8*)(h2r + 1 * 1024 + lane * 16);

        f32x4 a3 = MFMA(wfB[0], bA0, bv3);
        f32x4 a4 = MFMA(wfC[0], bA0, bv4);
        a3 = MFMA(wfB[1], bA1, a3);
        a4 = MFMA(wfC[1], bA1, a4);
        a3 = MFMA(wfB[2], bA2, a3);
        a4 = MFMA(wfC[2], bA2, a4);
        a3 = MFMA(wfB[3], bA3, a3);
        a4 = MFMA(wfC[3], bA3, a4);
        a3 = MFMA(wfB[4], bH0, a3);
        a4 = MFMA(wfC[4], bH0, a4);
        a3 = MFMA(wfB[5], bH1, a3);
        a4 = MFMA(wfC[5], bH1, a4);

        if (wv >= 1 && wv <= 5) {
            const float h3v = cellup(a3, cst3);
            if (ok3) hscr[hso3] = h3v;
        }
        {
            const float h4v = cellup(a4, cst4);
            hscr[hso4] = h4v;
        }
        __syncthreads();
    }

    // ---- dense head ----
    if (tid < ROWS) {
        float acc = bd[0];
#pragma unroll 2
        for (int u = 0; u < H2; ++u) acc = fmaf(hscr[tid * 52 + u], Wd[u], acc);
        out[row0 + tid] = acc;
    }
}

extern "C" void kernel_launch(void* const* d_in, const int* in_sizes, int n_in,
                              void* d_out, int out_size, void* d_ws, size_t ws_size,
                              hipStream_t stream) {
    const float* x     = (const float*)d_in[0];
    const float* W_ih1 = (const float*)d_in[1];
    const float* W_hh1 = (const float*)d_in[2];
    const float* b_ih1 = (const float*)d_in[3];
    const float* b_hh1 = (const float*)d_in[4];
    const float* W_ih2 = (const float*)d_in[5];
    const float* W_hh2 = (const float*)d_in[6];
    const float* b_ih2 = (const float*)d_in[7];
    const float* b_hh2 = (const float*)d_in[8];
    const float* Wd    = (const float*)d_in[9];
    const float* bd    = (const float*)d_in[10];
    float* out = (float*)d_out;

    hipLaunchKernelGGL(lstm_ws3, dim3(NBLK), dim3(NT), 0, stream,
                       x, W_ih1, W_hh1, b_ih1, b_hh1,
                       W_ih2, W_hh2, b_ih2, b_hh2, Wd, bd, out);
}

// Round 10
// 367.788 us; speedup vs baseline: 24.2042x; 1.0331x over previous
//
#include <hip/hip_runtime.h>
#include <math.h>

#define TT 256
#define H1 100
#define H2 50
#define NT 1024
#define NBLK 256   // 4096 rows / 16 per block; 1 block per CU
#define ROWS 16

typedef __attribute__((ext_vector_type(8))) short bf16x8;
typedef __attribute__((ext_vector_type(4))) float f32x4;

__device__ __forceinline__ float sigf(float x) {
    return __builtin_amdgcn_rcpf(1.0f + __expf(-x));
}
__device__ __forceinline__ float tanhfast(float x) {
    return 1.0f - 2.0f * __builtin_amdgcn_rcpf(1.0f + __expf(2.0f * x));
}
__device__ __forceinline__ short f2bf(float f) {
    union { float f; unsigned u; } v; v.f = f;
    unsigned r = v.u + 0x7FFFu + ((v.u >> 16) & 1u);  // RNE
    return (short)(r >> 16);
}

// fragment-linear byte offset: element (K,R) of a [chunk][64 lane][8 bf16] buf
__device__ __forceinline__ int off_frag(int K, int R) {
    return (K >> 5) * 1024 + ((K >> 3) & 3) * 256 + R * 16 + (K & 7) * 2;
}

#define MFMA(w, b, c) __builtin_amdgcn_mfma_f32_16x16x32_bf16(w, b, c, 0, 0, 0)

__device__ __forceinline__ float cellup(const f32x4& a, float& cst) {
    const float is = sigf(a[0]), fs = sigf(a[1]);
    const float gt = tanhfast(a[2]), os = sigf(a[3]);
    const float c = fs * cst + is * gt;
    cst = c;
    return os * tanhfast(c);
}

// ---- weight fragment loaders (round-4/7 proven numerics; run once) ----
__device__ __forceinline__ void load_w1(bf16x8* dst, int T, int r, int q,
                                        const float* W_hh1, const float* W_ih1) {
    const int jp = T * 16 + r, g = jp & 3, uu = jp >> 2;   // uu < 100
#pragma unroll
    for (int c = 0; c < 4; ++c) {
        bf16x8 w;
#pragma unroll
        for (int i = 0; i < 8; ++i) {
            const int k = c * 32 + q * 8 + i;
            float f = 0.f;
            if (k < H1) f = W_hh1[(g * H1 + uu) * H1 + k];
            else if (k < H1 + 8) f = W_ih1[(g * H1 + uu) * 8 + (k - H1)];
            w[i] = f2bf(f);
        }
        dst[c] = w;
    }
}
// L2 weights: chunks 0-3 (h1 part) -> dstA, chunks 4-5 (h2 part) -> dstH
__device__ __forceinline__ void load_w2(bf16x8* dstA, bf16x8* dstH, int t2,
                                        int r, int q,
                                        const float* W_ih2, const float* W_hh2) {
    const int jp = t2 * 16 + r, g = jp & 3, uu = jp >> 2;
    const bool ok = uu < H2;
#pragma unroll
    for (int c = 0; c < 4; ++c) {
        bf16x8 w;
#pragma unroll
        for (int i = 0; i < 8; ++i) {
            const int k = c * 32 + q * 8 + i;
            float f = 0.f;
            if (ok && k < H1) f = W_ih2[(g * H2 + uu) * H1 + k];
            w[i] = f2bf(f);
        }
        dstA[c] = w;
    }
#pragma unroll
    for (int c = 0; c < 2; ++c) {
        bf16x8 w;
#pragma unroll
        for (int i = 0; i < 8; ++i) {
            const int k2 = c * 32 + q * 8 + i;
            float f = 0.f;
            if (ok && k2 < H2) f = W_hh2[(g * H2 + uu) * H2 + k2];
            w[i] = f2bf(f);
        }
        dstH[c] = w;
    }
}

__global__ __launch_bounds__(NT) void lstm_ws5(
    const float* __restrict__ x,
    const float* __restrict__ W_ih1, const float* __restrict__ W_hh1,
    const float* __restrict__ b_ih1, const float* __restrict__ b_hh1,
    const float* __restrict__ W_ih2, const float* __restrict__ W_hh2,
    const float* __restrict__ b_ih2, const float* __restrict__ b_hh2,
    const float* __restrict__ Wd, const float* __restrict__ bd,
    float* __restrict__ out)
{
    __shared__ __align__(16) short xb[TT * ROWS * 8];   // 64 KB bf16 x
    __shared__ __align__(16) short A1h[2 * 4 * 64 * 8]; // 8 KB
    __shared__ __align__(16) short h2b[2 * 2 * 64 * 8]; // 4 KB
    __shared__ float hscr[ROWS * 52];

    const int tid = threadIdx.x;
    const int lane = tid & 63;
    const int wv = tid >> 6;       // 16 waves
    const int r = lane & 15;
    const int q = lane >> 4;
    const int row0 = blockIdx.x * ROWS;

    char* const a1b = (char*)A1h;
    char* const h2bb = (char*)h2b;

    // ---- fill xb ----
    {
        const float* xg = x + (size_t)row0 * (TT * 8);
#pragma unroll
        for (int it = 0; it < 8; ++it) {
            const int f = (it * NT + tid) * 4;
            const float4 v = *(const float4*)(xg + f);
            const int rr = f >> 11, rem = f & 2047, t = rem >> 3, k = rem & 7;
            uint2 pk;
            pk.x = (unsigned short)f2bf(v.x) | ((unsigned)(unsigned short)f2bf(v.y) << 16);
            pk.y = (unsigned short)f2bf(v.z) | ((unsigned)(unsigned short)f2bf(v.w) << 16);
            *(uint2*)((char*)xb + t * 256 + rr * 16 + k * 2) = pk;
        }
    }
    for (int i = tid; i < 2 * 4 * 64 * 8; i += NT) A1h[i] = 0;
    for (int i = tid; i < 2 * 2 * 64 * 8; i += NT) h2b[i] = 0;
    if (tid < ROWS * 52) hscr[tid] = 0.f;

    // ---- slot composition (38 tiles over 16 waves, zero dead slots) ----
    // slot0: L1 tile wv (0..15)                  -> always
    // slot1: wv<=8 -> L1 tile 16+wv (16..24); wv>=9 -> L2 tile wv-9 (0..6)
    // slot2: wv<=5 -> L2 tile 7+wv (7..12); else none
    const bool s1isL1 = (wv <= 8);
    const bool hasS2 = (wv <= 5);

    bf16x8 wf0[4], wf1[4], wf2[4], wH[2];
    // zero-init everything that is conditionally loaded: no operand is ever
    // formally uninitialized on any wave path.
    const bf16x8 zf = (bf16x8){0, 0, 0, 0, 0, 0, 0, 0};
#pragma unroll
    for (int c = 0; c < 4; ++c) wf2[c] = zf;
    wH[0] = zf; wH[1] = zf;

    f32x4 bv0, bv1, bv2 = {0.f, 0.f, 0.f, 0.f};
    int wof0, wof1, wof2 = 0;
    int hso1 = 0, hso2 = 0;
    bool ok2 = false;

    load_w1(wf0, wv, r, q, W_hh1, W_ih1);
    {
        const int u0 = wv * 4 + q;   // 0..63
#pragma unroll
        for (int g = 0; g < 4; ++g) bv0[g] = b_ih1[g * H1 + u0] + b_hh1[g * H1 + u0];
        wof0 = off_frag(u0, r);
    }
    if (s1isL1) {
        load_w1(wf1, 16 + wv, r, q, W_hh1, W_ih1);
        const int u1 = (16 + wv) * 4 + q;   // 64..99
#pragma unroll
        for (int g = 0; g < 4; ++g) bv1[g] = b_ih1[g * H1 + u1] + b_hh1[g * H1 + u1];
        wof1 = off_frag(u1, r);
    } else {
        load_w2(wf1, wH, wv - 9, r, q, W_ih2, W_hh2);
        const int u21 = (wv - 9) * 4 + q;   // 0..27, always < 50
#pragma unroll
        for (int g = 0; g < 4; ++g) bv1[g] = b_ih2[g * H2 + u21] + b_hh2[g * H2 + u21];
        wof1 = off_frag(u21, r);
        hso1 = r * 52 + u21;
    }
    if (hasS2) {
        load_w2(wf2, wH, 7 + wv, r, q, W_ih2, W_hh2);
        const int u22 = (7 + wv) * 4 + q;   // 28..51
        ok2 = (u22 < H2);
#pragma unroll
        for (int g = 0; g < 4; ++g)
            bv2[g] = ok2 ? (b_ih2[g * H2 + u22] + b_hh2[g * H2 + u22]) : 0.f;
        wof2 = off_frag(u22 & 63, r);
        hso2 = r * 52 + u22;
    }

    float cst0 = 0.f, cst1 = 0.f, cst2 = 0.f;

    const bool wstage = ((tid >> 4) == 60);   // wave 15, lanes 0..15
    const int st = tid & 15;

    __syncthreads();
    // stage x(0) into buf0 chunk 3
    if (tid < ROWS) {
        bf16x8 v = *(const bf16x8*)((const char*)xb + tid * 16);
        uint2 lo = ((const uint2*)&v)[0], hi = ((const uint2*)&v)[1];
        char* dst = a1b + 3 * 1024 + tid * 16;
        *(uint2*)(dst + 8) = lo;
        *(uint2*)(dst + 256) = hi;
    }
    __syncthreads();

    // ==== main loop: superstep s computes h1(s) and (s>0) h2(s-1) ====
    for (int s = 0; s < TT; ++s) {
        const int cur = s & 1;
        char* a1r = a1b + (cur << 12);
        char* h2r = h2bb + (cur << 11);
        char* a1w = a1b + ((cur ^ 1) << 12);
        char* h2w = h2bb + ((cur ^ 1) << 11);

        const bf16x8 bA0 = *(const bf16x8*)(a1r + 0 * 1024 + lane * 16);
        const bf16x8 bA1 = *(const bf16x8*)(a1r + 1 * 1024 + lane * 16);
        const bf16x8 bA2 = *(const bf16x8*)(a1r + 2 * 1024 + lane * 16);
        const bf16x8 bA3 = *(const bf16x8*)(a1r + 3 * 1024 + lane * 16);
        // unconditional: valid LDS for every wave; zeros when unused
        const bf16x8 bH0 = *(const bf16x8*)(h2r + 0 * 1024 + lane * 16);
        const bf16x8 bH1 = *(const bf16x8*)(h2r + 1 * 1024 + lane * 16);

        if (wstage && s + 1 < TT) {
            bf16x8 v = *(const bf16x8*)((const char*)xb + (s + 1) * 256 + st * 16);
            uint2 lo = ((const uint2*)&v)[0], hi = ((const uint2*)&v)[1];
            char* dst = a1w + 3 * 1024 + st * 16;
            *(uint2*)(dst + 8) = lo;
            *(uint2*)(dst + 256) = hi;
        }

        // ---- MFMAs: slots 0/1 two-way interleaved; slot2 after ----
        f32x4 a0 = MFMA(wf0[0], bA0, bv0);
        f32x4 a1 = MFMA(wf1[0], bA0, bv1);
        a0 = MFMA(wf0[1], bA1, a0);
        a1 = MFMA(wf1[1], bA1, a1);
        a0 = MFMA(wf0[2], bA2, a0);
        a1 = MFMA(wf1[2], bA2, a1);
        a0 = MFMA(wf0[3], bA3, a0);
        a1 = MFMA(wf1[3], bA3, a1);
        if (!s1isL1) {
            a1 = MFMA(wH[0], bH0, a1);
            a1 = MFMA(wH[1], bH1, a1);
        }
        f32x4 a2 = bv2;
        if (hasS2) {
            a2 = MFMA(wf2[0], bA0, a2);
            a2 = MFMA(wf2[1], bA1, a2);
            a2 = MFMA(wf2[2], bA2, a2);
            a2 = MFMA(wf2[3], bA3, a2);
            a2 = MFMA(wH[0], bH0, a2);
            a2 = MFMA(wH[1], bH1, a2);
        }

        // ---- nonlinearities + state writes ----
        const float h0 = cellup(a0, cst0);
        *(short*)(a1w + wof0) = f2bf(h0);

        if (s1isL1) {
            const float h1v = cellup(a1, cst1);
            *(short*)(a1w + wof1) = f2bf(h1v);
        } else if (s > 0) {
            const float h1v = cellup(a1, cst1);
            *(short*)(h2w + wof1) = f2bf(h1v);
        }
        if (hasS2 && s > 0) {
            const float h2v = cellup(a2, cst2);
            if (ok2) *(short*)(h2w + wof2) = f2bf(h2v);
        }
        __syncthreads();
    }

    // ==== peeled final superstep (s=256): L2 computes h2(255) -> hscr ====
    {
        char* a1r = a1b;      // s=256 even -> buf0
        char* h2r = h2bb;
        if (!s1isL1 || hasS2) {
            const bf16x8 bA0 = *(const bf16x8*)(a1r + 0 * 1024 + lane * 16);
            const bf16x8 bA1 = *(const bf16x8*)(a1r + 1 * 1024 + lane * 16);
            const bf16x8 bA2 = *(const bf16x8*)(a1r + 2 * 1024 + lane * 16);
            const bf16x8 bA3 = *(const bf16x8*)(a1r + 3 * 1024 + lane * 16);
            const bf16x8 bH0 = *(const bf16x8*)(h2r + 0 * 1024 + lane * 16);
            const bf16x8 bH1 = *(const bf16x8*)(h2r + 1 * 1024 + lane * 16);

            if (!s1isL1) {
                f32x4 a1 = MFMA(wf1[0], bA0, bv1);
                a1 = MFMA(wf1[1], bA1, a1);
                a1 = MFMA(wf1[2], bA2, a1);
                a1 = MFMA(wf1[3], bA3, a1);
                a1 = MFMA(wH[0], bH0, a1);
                a1 = MFMA(wH[1], bH1, a1);
                const float h1v = cellup(a1, cst1);
                hscr[hso1] = h1v;
            }
            if (hasS2) {
                f32x4 a2 = bv2;
                a2 = MFMA(wf2[0], bA0, a2);
                a2 = MFMA(wf2[1], bA1, a2);
                a2 = MFMA(wf2[2], bA2, a2);
                a2 = MFMA(wf2[3], bA3, a2);
                a2 = MFMA(wH[0], bH0, a2);
                a2 = MFMA(wH[1], bH1, a2);
                const float h2v = cellup(a2, cst2);
                if (ok2) hscr[hso2] = h2v;
            }
        }
        __syncthreads();
    }

    // ---- dense head ----
    if (tid < ROWS) {
        float acc = bd[0];
#pragma unroll 2
        for (int u = 0; u < H2; ++u) acc = fmaf(hscr[tid * 52 + u], Wd[u], acc);
        out[row0 + tid] = acc;
    }
}

extern "C" void kernel_launch(void* const* d_in, const int* in_sizes, int n_in,
                              void* d_out, int out_size, void* d_ws, size_t ws_size,
                              hipStream_t stream) {
    const float* x     = (const float*)d_in[0];
    const float* W_ih1 = (const float*)d_in[1];
    const float* W_hh1 = (const float*)d_in[2];
    const float* b_ih1 = (const float*)d_in[3];
    const float* b_hh1 = (const float*)d_in[4];
    const float* W_ih2 = (const float*)d_in[5];
    const float* W_hh2 = (const float*)d_in[6];
    const float* b_ih2 = (const float*)d_in[7];
    const float* b_hh2 = (const float*)d_in[8];
    const float* Wd    = (const float*)d_in[9];
    const float* bd    = (const float*)d_in[10];
    float* out = (float*)d_out;

    hipLaunchKernelGGL(lstm_ws5, dim3(NBLK), dim3(NT), 0, stream,
                       x, W_ih1, W_hh1, b_ih1, b_hh1,
                       W_ih2, W_hh2, b_ih2, b_hh2, Wd, bd, out);
}